// Round 5
// baseline (282.576 us; speedup 1.0000x reference)
//
#include <hip/hip_runtime.h>

// Problem constants
#define IN_DIM   256
#define CODE_LEN 128
#define MEM_LEN  65536
#define BETA     1.0f

// Output layout (floats): [0]=loss, [1..]=memory (MEM_LEN*CODE_LEN),
// then mem_data (MEM_LEN*IN_DIM), then mem_idx (MEM_LEN, as float)
#define OUT_MEM_OFF   1
#define OUT_MD_OFF    (1 + MEM_LEN*CODE_LEN)            // 8388609
#define OUT_IDX_OFF   (OUT_MD_OFF + MEM_LEN*IN_DIM)     // 25165825

// Workspace (float indices) — small, proven-safe footprint (~2.6 KB):
#define WS_COLSUM 0      // float[256]
#define WS_COLSQ  256    // float[256]
#define WS_ENC    512    // float[128]
#define WS_LOSS   640    // uint (init 0xFFFFFFFF)
#define WS_KEY    642    // u64 at byte 2568 (init all-ones)

#define MD_ELEMS  (MEM_LEN*IN_DIM)      // 16777216 floats = 64 MB
#define MEM_ELEMS (MEM_LEN*CODE_LEN)    // 8388608 floats = 32 MB

typedef float vfloat4 __attribute__((ext_vector_type(4)));

// ---------------------------------------------------------------------------
// init: zero colsum/colsq, set loss/key sentinels. 64 threads.
__global__ void k_init(float* __restrict__ ws) {
    const int t = threadIdx.x;
    #pragma unroll
    for (int j = 0; j < 8; ++j) ws[t + j * 64] = 0.f;   // 512 floats
    if (t == 0) {
        ((unsigned int*)ws)[WS_LOSS] = 0xFFFFFFFFu;
        *((unsigned long long*)(ws + WS_KEY)) = ~0ull;
    }
}

// ---------------------------------------------------------------------------
// A (PURE READ): blocks [0,1024): per-column sum/sumsq of mem_data.
//    16 aligned dwordx4 loads per thread (exact coverage: 1024*256*16 = 4M
//    tiles), no global stores at all — the copy is done by hipMemcpyAsync.
//    Tile stride 262144 is a multiple of 64 => each thread's 4 columns are
//    fixed: col base = (4t)&255.
//    blocks [1024,1088): mem_idx float-convert copy + packed argmin (the only
//    stores in this kernel, 0.25 MB).
__global__ __launch_bounds__(256, 8) void k_stats_read(
        const float* __restrict__ mem_data,
        const int*   __restrict__ mem_idx,
        float* __restrict__ out,
        float* __restrict__ ws) {
    const int t = threadIdx.x;
    const int bid = blockIdx.x;

    if (bid >= 1024) {
        __shared__ unsigned long long red[256];
        const int tid = (bid - 1024) * 256 + t;             // 0..16383
        unsigned long long local = ~0ull;
        #pragma unroll
        for (int rep = 0; rep < 4; ++rep) {
            int i = tid + rep * 16384;
            int v = mem_idx[i];
            out[OUT_IDX_OFF + i] = (float)v;
            unsigned long long key =
                (((unsigned long long)(unsigned int)(v ^ (int)0x80000000)) << 32)
                | (unsigned int)i;
            local = local < key ? local : key;
        }
        red[t] = local;
        __syncthreads();
        for (int s = 128; s > 0; s >>= 1) {
            if (t < s) { unsigned long long o = red[t + s]; if (o < red[t]) red[t] = o; }
            __syncthreads();
        }
        if (t == 0) atomicMin((unsigned long long*)(ws + WS_KEY), red[0]);
        return;
    }

    __shared__ float lsum[256], lsq[256];
    lsum[t] = 0.f; lsq[t] = 0.f;

    const int gtid = bid * 256 + t;                         // 0..262143
    float s0=0,s1=0,s2=0,s3=0,q0=0,q1=0,q2=0,q3=0;

    vfloat4 v[16];
    #pragma unroll
    for (int j = 0; j < 16; ++j)
        v[j] = ((const vfloat4*)mem_data)[gtid + j * 262144];   // aligned dwordx4
    #pragma unroll
    for (int j = 0; j < 16; ++j) {
        s0 += v[j].x; q0 += v[j].x * v[j].x;
        s1 += v[j].y; q1 += v[j].y * v[j].y;
        s2 += v[j].z; q2 += v[j].z * v[j].z;
        s3 += v[j].w; q3 += v[j].w * v[j].w;
    }

    __syncthreads();
    const int c0 = (4 * t) & 255;                           // c0 <= 252, no wrap
    atomicAdd(&lsum[c0    ], s0);  atomicAdd(&lsq[c0    ], q0);
    atomicAdd(&lsum[c0 + 1], s1);  atomicAdd(&lsq[c0 + 1], q1);
    atomicAdd(&lsum[c0 + 2], s2);  atomicAdd(&lsq[c0 + 2], q2);
    atomicAdd(&lsum[c0 + 3], s3);  atomicAdd(&lsq[c0 + 3], q3);
    __syncthreads();
    atomicAdd(&ws[WS_COLSUM + t], lsum[t]);
    atomicAdd(&ws[WS_COLSQ  + t], lsq[t]);
}

// ---------------------------------------------------------------------------
// B: mean/std -> normalize x -> enc = new @ W^T + b.  1 block x 256 threads.
__global__ void k_enc(const float* __restrict__ x,
                      const float* __restrict__ W,
                      const float* __restrict__ b,
                      float* __restrict__ ws) {
    __shared__ float nrm[IN_DIM];
    const int t = threadIdx.x;
    float sum = ws[WS_COLSUM + t];
    float sq  = ws[WS_COLSQ + t];
    float mean = sum * (1.0f / MEM_LEN);
    float var  = (sq - sum * sum * (1.0f / MEM_LEN)) * (1.0f / (MEM_LEN - 1));
    var = fmaxf(var, 0.0f);
    float sd = sqrtf(var);
    nrm[t] = (sd == 0.0f) ? 0.0f : (x[t] - mean) / sd;
    __syncthreads();
    if (t < CODE_LEN) {
        float acc = b[t];
        const float* w = W + t * IN_DIM;
        #pragma unroll 8
        for (int d = 0; d < IN_DIM; ++d) acc += nrm[d] * w[d];
        ws[WS_ENC + t] = acc;
    }
}

// ---------------------------------------------------------------------------
// C (PURE READ): L1 distance per row + global min. No stores — the memory
//    copy is done by hipMemcpyAsync (and that copy ran earlier, so memory is
//    Infinity-Cache-resident for these reads). 1024 blocks, 8 rows per
//    32-lane group (8*8192 = 65536 rows exact).
__global__ __launch_bounds__(256, 8) void k_dist_read(
        const float* __restrict__ memory,
        float* __restrict__ ws) {
    __shared__ vfloat4 es[32];
    __shared__ float red[256];
    const int t = threadIdx.x;
    if (t < 32) es[t] = ((const vfloat4*)(ws + WS_ENC))[t];
    __syncthreads();
    const int lane = t & 31;
    const int grp  = t >> 5;
    const vfloat4 e = es[lane];
    float localmin = 3.4e38f;

    vfloat4 m[8];
    #pragma unroll
    for (int i = 0; i < 8; ++i) {
        const int row = i * 8192 + blockIdx.x * 8 + grp;
        m[i] = ((const vfloat4*)memory)[row * 32 + lane];        // aligned
    }
    #pragma unroll
    for (int i = 0; i < 8; ++i) {
        float d = fabsf(m[i].x - e.x) + fabsf(m[i].y - e.y)
                + fabsf(m[i].z - e.z) + fabsf(m[i].w - e.w);
        #pragma unroll
        for (int off = 16; off > 0; off >>= 1) d += __shfl_xor(d, off, 32);
        localmin = fminf(localmin, d);
    }

    red[t] = localmin;
    __syncthreads();
    for (int s2 = 128; s2 > 0; s2 >>= 1) {
        if (t < s2) red[t] = fminf(red[t], red[t + s2]);
        __syncthreads();
    }
    if (t == 0)
        atomicMin((unsigned int*)(ws + WS_LOSS), __float_as_uint(red[0]));
}

// ---------------------------------------------------------------------------
// E: write loss; conditional scatter update. 1 block x 256 threads.
//    Runs after both memcpys (stream order), so the scatter lands on top of
//    the copied arrays.
__global__ void k_final(const float* __restrict__ x,
                        const int* __restrict__ count,
                        const float* __restrict__ ws,
                        float* __restrict__ d_out) {
    const int t = threadIdx.x;
    const float loss = __uint_as_float(((const unsigned int*)ws)[WS_LOSS]);
    if (t == 0) d_out[0] = loss;
    if (loss <= BETA) {
        unsigned long long key = *(const unsigned long long*)(ws + WS_KEY);
        unsigned int pos = (unsigned int)(key & 0xFFFFFFFFull);
        if (t < CODE_LEN)
            d_out[OUT_MEM_OFF + (size_t)pos * CODE_LEN + t] = ws[WS_ENC + t];
        d_out[OUT_MD_OFF + (size_t)pos * IN_DIM + t] = x[t];
        if (t == 0)
            d_out[OUT_IDX_OFF + pos] = (float)count[0];
    }
}

// ---------------------------------------------------------------------------
extern "C" void kernel_launch(void* const* d_in, const int* in_sizes, int n_in,
                              void* d_out, int out_size, void* d_ws, size_t ws_size,
                              hipStream_t stream) {
    const float* x        = (const float*)d_in[0];
    const float* memory   = (const float*)d_in[1];
    const float* mem_data = (const float*)d_in[2];
    const int*   mem_idx  = (const int*)d_in[3];
    const float* W        = (const float*)d_in[4];
    const float* b        = (const float*)d_in[5];
    const int*   count    = (const int*)d_in[6];
    float* out = (float*)d_out;
    float* ws  = (float*)d_ws;

    k_init<<<1, 64, 0, stream>>>(ws);

    // Bulk copies via the runtime's blit path (pure write-stream separation;
    // hipMemcpyAsync on the capture stream is the sanctioned pattern).
    hipMemcpyAsync(out + OUT_MD_OFF,  mem_data, (size_t)MD_ELEMS  * 4,
                   hipMemcpyDeviceToDevice, stream);
    hipMemcpyAsync(out + OUT_MEM_OFF, memory,   (size_t)MEM_ELEMS * 4,
                   hipMemcpyDeviceToDevice, stream);

    k_stats_read<<<1088, 256, 0, stream>>>(mem_data, mem_idx, out, ws);
    k_enc<<<1, 256, 0, stream>>>(x, W, b, ws);
    k_dist_read<<<1024, 256, 0, stream>>>(memory, ws);
    k_final<<<1, 256, 0, stream>>>(x, count, ws, out);
}

// Round 6
// 261.897 us; speedup vs baseline: 1.0790x; 1.0790x over previous
//
#include <hip/hip_runtime.h>

// Problem constants
#define IN_DIM   256
#define CODE_LEN 128
#define MEM_LEN  65536
#define BETA     1.0f

// Output layout (floats): [0]=loss, [1..]=memory (MEM_LEN*CODE_LEN),
// then mem_data (MEM_LEN*IN_DIM), then mem_idx (MEM_LEN, as float)
#define OUT_MEM_OFF   1
#define OUT_MD_OFF    (1 + MEM_LEN*CODE_LEN)            // 8388609
#define OUT_IDX_OFF   (OUT_MD_OFF + MEM_LEN*IN_DIM)     // 25165825

// Workspace (float indices):
#define WS_COLSUM 0      // float[256]
#define WS_COLSQ  256    // float[256]
#define WS_ENC    512    // float[128]
#define WS_LOSS   640    // uint (init 0xFFFFFFFF)
#define WS_KEY    642    // u64 at byte 2568 (init all-ones)

#define MD_ELEMS   (MEM_LEN*IN_DIM)     // 16777216 floats = 64 MB
#define MEM_ELEMS  (MEM_LEN*CODE_LEN)   // 8388608 floats = 32 MB
#define MD_SRC_T   (MD_ELEMS/4)         // 4194304 aligned src tiles
#define MD_DST_T   (MD_SRC_T - 1)       // 4194303 aligned dst tiles (phase 3)
#define MEM_SRC_T  (MEM_ELEMS/4)        // 2097152
#define MEM_DST_T  (MEM_SRC_T - 1)      // 2097151

typedef float vfloat4 __attribute__((ext_vector_type(4)));

// ---------------------------------------------------------------------------
// init: zero colsum/colsq, set loss/key sentinels. 64 threads.
__global__ void k_init(float* __restrict__ ws) {
    const int t = threadIdx.x;
    #pragma unroll
    for (int j = 0; j < 8; ++j) ws[t + j * 64] = 0.f;   // 512 floats
    if (t == 0) {
        ((unsigned int*)ws)[WS_LOSS] = 0xFFFFFFFFu;
        *((unsigned long long*)(ws + WS_KEY)) = ~0ull;
    }
}

// ---------------------------------------------------------------------------
// COPY-MD (PURE, both streams 16B-aligned): dst tile k = out_md[3+4k..6+4k]
//   (out_md+3 is 16B-aligned) <- {srcT[k].w, srcT[k+1].xyz}. The 4B relative
//   phase is absorbed in-register: lane l loads aligned srcT[K0+l]; the
//   neighbor tile comes from lane l+1 via 3 __shfl; lane 63 loads one extra
//   tile. No LDS, no barriers, no atomics, no stats — m13-copy-equivalent.
//   2048 copy blocks x 8 wave-iters; blocks [2048,2112): mem_idx copy+argmin.
__global__ __launch_bounds__(256, 8) void k_copy_md(
        const float* __restrict__ mem_data,
        const int*   __restrict__ mem_idx,
        float* __restrict__ out,
        float* __restrict__ ws) {
    const int t = threadIdx.x;
    const int bid = blockIdx.x;

    if (bid >= 2048) {
        __shared__ unsigned long long red[256];
        const int tid = (bid - 2048) * 256 + t;             // 0..16383
        unsigned long long local = ~0ull;
        #pragma unroll
        for (int rep = 0; rep < 4; ++rep) {
            int i = tid + rep * 16384;
            int v = mem_idx[i];
            out[OUT_IDX_OFF + i] = (float)v;
            unsigned long long key =
                (((unsigned long long)(unsigned int)(v ^ (int)0x80000000)) << 32)
                | (unsigned int)i;
            local = local < key ? local : key;
        }
        red[t] = local;
        __syncthreads();
        for (int s = 128; s > 0; s >>= 1) {
            if (t < s) { unsigned long long o = red[t + s]; if (o < red[t]) red[t] = o; }
            __syncthreads();
        }
        if (t == 0) atomicMin((unsigned long long*)(ws + WS_KEY), red[0]);
        return;
    }

    const vfloat4* __restrict__ src4 = (const vfloat4*)mem_data;
    float* __restrict__ out_md = out + OUT_MD_OFF;
    vfloat4* __restrict__ dst4 = (vfloat4*)(out_md + 3);    // 16B-aligned
    const int w = t >> 6, l = t & 63;
    const int gw = bid * 4 + w;                             // 0..8191

    #pragma unroll
    for (int i = 0; i < 8; ++i) {
        const int k = (gw + i * 8192) * 64 + l;             // 0..4194303
        vfloat4 v = src4[k];
        vfloat4 e4;
        if (l == 63) e4 = src4[(k + 1 < MD_SRC_T) ? k + 1 : 0];
        float nx = __shfl(v.x, l + 1, 64);                  // lane 63 wraps: fixed below
        float ny = __shfl(v.y, l + 1, 64);
        float nz = __shfl(v.z, l + 1, 64);
        if (l == 63) { nx = e4.x; ny = e4.y; nz = e4.z; }
        vfloat4 d; d.x = v.w; d.y = nx; d.z = ny; d.w = nz;
        if (k < MD_DST_T) dst4[k] = d;                      // aligned store
    }

    if (bid == 0 && t == 0) {   // edges not covered by dst tiles
        out_md[0] = mem_data[0];
        out_md[1] = mem_data[1];
        out_md[2] = mem_data[2];
        out_md[MD_ELEMS - 1] = mem_data[MD_ELEMS - 1];
    }
}

// ---------------------------------------------------------------------------
// STATS (PURE READ): per-column sum/sumsq of mem_data — runs right after
//   k_copy_md streamed these exact lines, so reads are L3-resident.
//   Same index/summation order as the R3 kernel (absmax 0.0 verified).
__global__ __launch_bounds__(256, 8) void k_stats_read(
        const float* __restrict__ mem_data,
        float* __restrict__ ws) {
    const int t = threadIdx.x;
    __shared__ float lsum[256], lsq[256];
    lsum[t] = 0.f; lsq[t] = 0.f;

    const int gtid = blockIdx.x * 256 + t;                  // 0..262143
    float s0=0,s1=0,s2=0,s3=0,q0=0,q1=0,q2=0,q3=0;

    vfloat4 v[16];
    #pragma unroll
    for (int j = 0; j < 16; ++j)
        v[j] = ((const vfloat4*)mem_data)[gtid + j * 262144];   // aligned
    #pragma unroll
    for (int j = 0; j < 16; ++j) {
        s0 += v[j].x; q0 += v[j].x * v[j].x;
        s1 += v[j].y; q1 += v[j].y * v[j].y;
        s2 += v[j].z; q2 += v[j].z * v[j].z;
        s3 += v[j].w; q3 += v[j].w * v[j].w;
    }

    __syncthreads();
    const int c0 = (4 * t) & 255;                           // c0 <= 252, no wrap
    atomicAdd(&lsum[c0    ], s0);  atomicAdd(&lsq[c0    ], q0);
    atomicAdd(&lsum[c0 + 1], s1);  atomicAdd(&lsq[c0 + 1], q1);
    atomicAdd(&lsum[c0 + 2], s2);  atomicAdd(&lsq[c0 + 2], q2);
    atomicAdd(&lsum[c0 + 3], s3);  atomicAdd(&lsq[c0 + 3], q3);
    __syncthreads();
    atomicAdd(&ws[WS_COLSUM + t], lsum[t]);
    atomicAdd(&ws[WS_COLSQ  + t], lsq[t]);
}

// ---------------------------------------------------------------------------
// B: mean/std -> normalize x -> enc = new @ W^T + b.  1 block x 256 threads.
__global__ void k_enc(const float* __restrict__ x,
                      const float* __restrict__ W,
                      const float* __restrict__ b,
                      float* __restrict__ ws) {
    __shared__ float nrm[IN_DIM];
    const int t = threadIdx.x;
    float sum = ws[WS_COLSUM + t];
    float sq  = ws[WS_COLSQ + t];
    float mean = sum * (1.0f / MEM_LEN);
    float var  = (sq - sum * sum * (1.0f / MEM_LEN)) * (1.0f / (MEM_LEN - 1));
    var = fmaxf(var, 0.0f);
    float sd = sqrtf(var);
    nrm[t] = (sd == 0.0f) ? 0.0f : (x[t] - mean) / sd;
    __syncthreads();
    if (t < CODE_LEN) {
        float acc = b[t];
        const float* w = W + t * IN_DIM;
        #pragma unroll 8
        for (int d = 0; d < IN_DIM; ++d) acc += nrm[d] * w[d];
        ws[WS_ENC + t] = acc;
    }
}

// ---------------------------------------------------------------------------
// COPY-MEM (PURE, both streams aligned): same shfl-phase-fix pattern.
//   dst tile k = out[4+4k..7+4k] (out+4 is 16B-aligned) <- memory[3+4k..6+4k].
__global__ __launch_bounds__(256, 8) void k_copy_mem(
        const float* __restrict__ memory,
        float* __restrict__ out) {
    const int t = threadIdx.x;
    const int bid = blockIdx.x;
    const vfloat4* __restrict__ src4 = (const vfloat4*)memory;
    vfloat4* __restrict__ dst4 = (vfloat4*)(out + OUT_MEM_OFF + 3);  // out+4, aligned
    const int w = t >> 6, l = t & 63;
    const int gw = bid * 4 + w;                             // 0..4095

    #pragma unroll
    for (int i = 0; i < 8; ++i) {
        const int k = (gw + i * 4096) * 64 + l;             // 0..2097151
        vfloat4 v = src4[k];
        vfloat4 e4;
        if (l == 63) e4 = src4[(k + 1 < MEM_SRC_T) ? k + 1 : 0];
        float nx = __shfl(v.x, l + 1, 64);
        float ny = __shfl(v.y, l + 1, 64);
        float nz = __shfl(v.z, l + 1, 64);
        if (l == 63) { nx = e4.x; ny = e4.y; nz = e4.z; }
        vfloat4 d; d.x = v.w; d.y = nx; d.z = ny; d.w = nz;
        if (k < MEM_DST_T) dst4[k] = d;
    }

    if (bid == 0 && t == 0) {
        out[OUT_MEM_OFF + 0] = memory[0];
        out[OUT_MEM_OFF + 1] = memory[1];
        out[OUT_MEM_OFF + 2] = memory[2];
        out[OUT_MEM_OFF + MEM_ELEMS - 1] = memory[MEM_ELEMS - 1];
    }
}

// ---------------------------------------------------------------------------
// DIST (PURE READ): L1 distance per row + global min — runs right after
//   k_copy_mem streamed memory, so reads are L3-resident. Verified in R5.
__global__ __launch_bounds__(256, 8) void k_dist_read(
        const float* __restrict__ memory,
        float* __restrict__ ws) {
    __shared__ vfloat4 es[32];
    __shared__ float red[256];
    const int t = threadIdx.x;
    if (t < 32) es[t] = ((const vfloat4*)(ws + WS_ENC))[t];
    __syncthreads();
    const int lane = t & 31;
    const int grp  = t >> 5;
    const vfloat4 e = es[lane];
    float localmin = 3.4e38f;

    vfloat4 m[8];
    #pragma unroll
    for (int i = 0; i < 8; ++i) {
        const int row = i * 8192 + blockIdx.x * 8 + grp;
        m[i] = ((const vfloat4*)memory)[row * 32 + lane];        // aligned
    }
    #pragma unroll
    for (int i = 0; i < 8; ++i) {
        float d = fabsf(m[i].x - e.x) + fabsf(m[i].y - e.y)
                + fabsf(m[i].z - e.z) + fabsf(m[i].w - e.w);
        #pragma unroll
        for (int off = 16; off > 0; off >>= 1) d += __shfl_xor(d, off, 32);
        localmin = fminf(localmin, d);
    }

    red[t] = localmin;
    __syncthreads();
    for (int s2 = 128; s2 > 0; s2 >>= 1) {
        if (t < s2) red[t] = fminf(red[t], red[t + s2]);
        __syncthreads();
    }
    if (t == 0)
        atomicMin((unsigned int*)(ws + WS_LOSS), __float_as_uint(red[0]));
}

// ---------------------------------------------------------------------------
// E: write loss; conditional scatter update. 1 block x 256 threads.
__global__ void k_final(const float* __restrict__ x,
                        const int* __restrict__ count,
                        const float* __restrict__ ws,
                        float* __restrict__ d_out) {
    const int t = threadIdx.x;
    const float loss = __uint_as_float(((const unsigned int*)ws)[WS_LOSS]);
    if (t == 0) d_out[0] = loss;
    if (loss <= BETA) {
        unsigned long long key = *(const unsigned long long*)(ws + WS_KEY);
        unsigned int pos = (unsigned int)(key & 0xFFFFFFFFull);
        if (t < CODE_LEN)
            d_out[OUT_MEM_OFF + (size_t)pos * CODE_LEN + t] = ws[WS_ENC + t];
        d_out[OUT_MD_OFF + (size_t)pos * IN_DIM + t] = x[t];
        if (t == 0)
            d_out[OUT_IDX_OFF + pos] = (float)count[0];
    }
}

// ---------------------------------------------------------------------------
extern "C" void kernel_launch(void* const* d_in, const int* in_sizes, int n_in,
                              void* d_out, int out_size, void* d_ws, size_t ws_size,
                              hipStream_t stream) {
    const float* x        = (const float*)d_in[0];
    const float* memory   = (const float*)d_in[1];
    const float* mem_data = (const float*)d_in[2];
    const int*   mem_idx  = (const int*)d_in[3];
    const float* W        = (const float*)d_in[4];
    const float* b        = (const float*)d_in[5];
    const int*   count    = (const int*)d_in[6];
    float* out = (float*)d_out;
    float* ws  = (float*)d_ws;

    k_init<<<1, 64, 0, stream>>>(ws);
    k_copy_md<<<2112, 256, 0, stream>>>(mem_data, mem_idx, out, ws);
    k_stats_read<<<1024, 256, 0, stream>>>(mem_data, ws);
    k_enc<<<1, 256, 0, stream>>>(x, W, b, ws);
    k_copy_mem<<<1024, 256, 0, stream>>>(memory, out);
    k_dist_read<<<1024, 256, 0, stream>>>(memory, ws);
    k_final<<<1, 256, 0, stream>>>(x, count, ws, out);
}

// Round 7
// 218.693 us; speedup vs baseline: 1.2921x; 1.1976x over previous
//
#include <hip/hip_runtime.h>
#include <hip/hip_bf16.h>

// Problem constants
#define IN_DIM   256
#define CODE_LEN 128
#define MEM_LEN  65536
#define BETA     1.0f

// Output layout (floats): [0]=loss, [1..]=memory (MEM_LEN*CODE_LEN),
// then mem_data (MEM_LEN*IN_DIM), then mem_idx (MEM_LEN, as float)
#define OUT_MEM_OFF   1
#define OUT_MD_OFF    (1 + MEM_LEN*CODE_LEN)            // 8388609
#define OUT_IDX_OFF   (OUT_MD_OFF + MEM_LEN*IN_DIM)     // 25165825

// Workspace (float indices):
#define WS_COLSUM 0      // float[256]
#define WS_COLSQ  256    // float[256]
#define WS_ENC    512    // float[128]
#define WS_LOSS   640    // uint (init 0xFFFFFFFF)
#define WS_KEY    642    // u64 at byte 2568 (init all-ones)
#define WS_CTR2   644    // uint: stats-kernel completion counter (init 0)

#define MD_ELEMS  (MEM_LEN*IN_DIM)     // 16777216
#define MD_TILES  (MD_ELEMS/4)         // 4194304 aligned source tiles — EXACT
#define MEM_ELEMS (MEM_LEN*CODE_LEN)   // 8388608
#define MEM_TILES (MEM_ELEMS/4)        // 2097152 aligned source tiles — EXACT

// native clang vector type
typedef float vfloat4 __attribute__((ext_vector_type(4)));

// Unaligned (4B-phase) 16-byte store: dst is float* (align 4). Misaligned
// writes merge in L2; this lets all LOADS be 16B-aligned dwordx4. Proven
// equivalent to every other instruction-level variant (R0-R6), and this
// arrangement (fused single-pass, each byte touched once) is the traffic-
// optimal one: 192.5 MB compulsory, measured best (222.8 us).
__device__ __forceinline__ void store16u(float* dst, vfloat4 v) {
    __builtin_memcpy(dst, &v, 16);
}

// ---------------------------------------------------------------------------
// init: zero colsum/colsq, set loss/key sentinels, zero completion counter.
__global__ void k_init(float* __restrict__ ws) {
    const int t = threadIdx.x;            // 64 threads
    #pragma unroll
    for (int j = 0; j < 8; ++j) ws[t + j * 64] = 0.f;   // 512 floats
    if (t == 0) {
        ((unsigned int*)ws)[WS_LOSS] = 0xFFFFFFFFu;
        *((unsigned long long*)(ws + WS_KEY)) = ~0ull;
        ((unsigned int*)ws)[WS_CTR2] = 0u;
    }
}

// ---------------------------------------------------------------------------
// A (+enc fold): blocks [0,1024): copy mem_data -> out + per-column sum/sumsq.
//    Source-aligned tiling: tile k = 16B-aligned dwordx4 load of
//    mem_data[4k..4k+3]; store misaligned to out_md+4k. Exact coverage
//    (1024*256*16 == MD_TILES): no bounds checks, no edge fixups.
//    All 16 loads issue into independent registers, then 16 plain stores +
//    accumulation. Stride 262144 tiles keeps each thread's 4 columns fixed:
//    col base = (4t)&255.
//    blocks [1024,1088): mem_idx copy + packed argmin.
//    Last-finishing block (device-scope counter) computes mean/std -> nrm ->
//    enc = nrm @ W^T + b (former k_enc, bit-identical arithmetic).
__global__ __launch_bounds__(256, 4) void k_stats_enc(
        const float* __restrict__ x,
        const float* __restrict__ mem_data,
        const int*   __restrict__ mem_idx,
        const float* __restrict__ W,
        const float* __restrict__ b,
        float* __restrict__ out,
        float* __restrict__ ws) {
    const int t = threadIdx.x;

    if (blockIdx.x >= 1024) {
        __shared__ unsigned long long red[256];
        const int tid = (blockIdx.x - 1024) * 256 + t;      // 0..16383
        unsigned long long local = ~0ull;
        #pragma unroll
        for (int rep = 0; rep < 4; ++rep) {
            int i = tid + rep * 16384;
            int v = mem_idx[i];
            out[OUT_IDX_OFF + i] = (float)v;
            unsigned long long key =
                (((unsigned long long)(unsigned int)(v ^ (int)0x80000000)) << 32)
                | (unsigned int)i;
            local = local < key ? local : key;
        }
        red[t] = local;
        __syncthreads();
        for (int s = 128; s > 0; s >>= 1) {
            if (t < s) { unsigned long long o = red[t + s]; if (o < red[t]) red[t] = o; }
            __syncthreads();
        }
        if (t == 0) atomicMin((unsigned long long*)(ws + WS_KEY), red[0]);
    } else {
        __shared__ float lsum[256], lsq[256];
        float* __restrict__ out_md = out + OUT_MD_OFF;
        const int t0 = blockIdx.x * 256 + t;                // 0..262143
        float s0=0,s1=0,s2=0,s3=0,q0=0,q1=0,q2=0,q3=0;

        vfloat4 v[16];
        #pragma unroll
        for (int j = 0; j < 16; ++j)
            v[j] = ((const vfloat4*)mem_data)[t0 + j * 262144];   // aligned dwordx4
        #pragma unroll
        for (int j = 0; j < 16; ++j) {
            const int k = t0 + j * 262144;
            store16u(out_md + 4 * k, v[j]);                       // plain, unaligned
            s0 += v[j].x; q0 += v[j].x * v[j].x;
            s1 += v[j].y; q1 += v[j].y * v[j].y;
            s2 += v[j].z; q2 += v[j].z * v[j].z;
            s3 += v[j].w; q3 += v[j].w * v[j].w;
        }

        lsum[t] = 0.f; lsq[t] = 0.f;
        __syncthreads();
        const int c0 = (4 * t) & 255;                       // no wrap: c0 <= 252
        atomicAdd(&lsum[c0    ], s0);  atomicAdd(&lsq[c0    ], q0);
        atomicAdd(&lsum[c0 + 1], s1);  atomicAdd(&lsq[c0 + 1], q1);
        atomicAdd(&lsum[c0 + 2], s2);  atomicAdd(&lsq[c0 + 2], q2);
        atomicAdd(&lsum[c0 + 3], s3);  atomicAdd(&lsq[c0 + 3], q3);
        __syncthreads();
        atomicAdd(&ws[WS_COLSUM + t], lsum[t]);
        atomicAdd(&ws[WS_COLSQ  + t], lsq[t]);
    }

    // ---- completion detection: last of 1088 blocks computes enc ----
    asm volatile("s_waitcnt vmcnt(0)" ::: "memory");  // own stores/atomics drained
    __syncthreads();                                  // whole block drained
    __shared__ unsigned int s_last;
    if (t == 0)
        s_last = (atomicAdd(&((unsigned int*)ws)[WS_CTR2], 1u) == 1087u) ? 1u : 0u;
    __syncthreads();
    if (!s_last) return;

    // ---- former k_enc, bit-identical arithmetic ----
    __shared__ float nrm[IN_DIM];
    {
        // identity atomics = guaranteed-coherent read of the accumulators
        float sum = atomicAdd(&ws[WS_COLSUM + t], 0.0f);
        float sq  = atomicAdd(&ws[WS_COLSQ  + t], 0.0f);
        float mean = sum * (1.0f / MEM_LEN);
        float var  = (sq - sum * sum * (1.0f / MEM_LEN)) * (1.0f / (MEM_LEN - 1));
        var = fmaxf(var, 0.0f);
        float sd = sqrtf(var);
        nrm[t] = (sd == 0.0f) ? 0.0f : (x[t] - mean) / sd;
    }
    __syncthreads();
    if (t < CODE_LEN) {
        float acc = b[t];
        const float* w = W + t * IN_DIM;
        #pragma unroll 8
        for (int d = 0; d < IN_DIM; ++d) acc += nrm[d] * w[d];
        ws[WS_ENC + t] = acc;
    }
}

// ---------------------------------------------------------------------------
// C: memory copy + L1 distance per row + global min.
//    Source-aligned tiling: ONE aligned dwordx4 load per tile serves BOTH the
//    distance math and the (misaligned, plain) store. Exact coverage:
//    1024*256*8 == MEM_TILES.
//    (Epilogue stays a separate dispatch: its scatter overwrites lines
//    written by other XCDs — the kernel boundary is the cheapest flush.)
__global__ __launch_bounds__(256, 4) void k_dist_copy(
        const float* __restrict__ memory,
        float* __restrict__ out,
        float* __restrict__ ws) {
    __shared__ vfloat4 es[32];
    __shared__ float red[256];
    const int t = threadIdx.x;
    if (t < 32) es[t] = ((const vfloat4*)(ws + WS_ENC))[t];
    __syncthreads();
    const int lane = t & 31;
    const int grp  = t >> 5;
    const vfloat4 e = es[lane];
    float* __restrict__ out_mem = out + OUT_MEM_OFF;   // 4B-aligned only
    float localmin = 3.4e38f;
    #pragma unroll
    for (int half = 0; half < 2; ++half) {
        vfloat4 m[4];
        int idx[4];
        #pragma unroll
        for (int sw = 0; sw < 4; ++sw) {
            const int row = (half * 4 + sw) * 8192 + blockIdx.x * 8 + grp;
            const int i = row * 32 + lane;
            idx[sw] = i;
            m[sw] = ((const vfloat4*)memory)[i];             // aligned dwordx4
        }
        #pragma unroll
        for (int sw = 0; sw < 4; ++sw) {
            const int i = idx[sw];
            store16u(out_mem + 4 * i, m[sw]);                // plain, unaligned
            float d = fabsf(m[sw].x-e.x) + fabsf(m[sw].y-e.y)
                    + fabsf(m[sw].z-e.z) + fabsf(m[sw].w-e.w);
            #pragma unroll
            for (int off = 16; off > 0; off >>= 1) d += __shfl_xor(d, off, 32);
            localmin = fminf(localmin, d);
        }
    }
    red[t] = localmin;
    __syncthreads();
    for (int s2 = 128; s2 > 0; s2 >>= 1) {
        if (t < s2) red[t] = fminf(red[t], red[t + s2]);
        __syncthreads();
    }
    if (t == 0)
        atomicMin((unsigned int*)(ws + WS_LOSS), __float_as_uint(red[0]));
}

// ---------------------------------------------------------------------------
// E: write loss; conditional scatter update. 1 block x 256 threads.
__global__ void k_final(const float* __restrict__ x,
                        const int* __restrict__ count,
                        const float* __restrict__ ws,
                        float* __restrict__ d_out) {
    const int t = threadIdx.x;
    const float loss = __uint_as_float(((const unsigned int*)ws)[WS_LOSS]);
    if (t == 0) d_out[0] = loss;
    if (loss <= BETA) {
        unsigned long long key = *(const unsigned long long*)(ws + WS_KEY);
        unsigned int pos = (unsigned int)(key & 0xFFFFFFFFull);
        if (t < CODE_LEN)
            d_out[OUT_MEM_OFF + (size_t)pos * CODE_LEN + t] = ws[WS_ENC + t];
        d_out[OUT_MD_OFF + (size_t)pos * IN_DIM + t] = x[t];
        if (t == 0)
            d_out[OUT_IDX_OFF + pos] = (float)count[0];
    }
}

// ---------------------------------------------------------------------------
extern "C" void kernel_launch(void* const* d_in, const int* in_sizes, int n_in,
                              void* d_out, int out_size, void* d_ws, size_t ws_size,
                              hipStream_t stream) {
    const float* x        = (const float*)d_in[0];
    const float* memory   = (const float*)d_in[1];
    const float* mem_data = (const float*)d_in[2];
    const int*   mem_idx  = (const int*)d_in[3];
    const float* W        = (const float*)d_in[4];
    const float* b        = (const float*)d_in[5];
    const int*   count    = (const int*)d_in[6];
    float* out = (float*)d_out;
    float* ws  = (float*)d_ws;

    k_init<<<1, 64, 0, stream>>>(ws);
    k_stats_enc<<<1088, 256, 0, stream>>>(x, mem_data, mem_idx, W, b, out, ws);
    k_dist_copy<<<1024, 256, 0, stream>>>(memory, out, ws);
    k_final<<<1, 256, 0, stream>>>(x, count, ws, out);
}